// Round 1
// baseline (266.071 us; speedup 1.0000x reference)
//
#include <hip/hip_runtime.h>

typedef __attribute__((ext_vector_type(8))) short s16x8;
typedef __attribute__((ext_vector_type(4))) float f32x4;

constexpr int B_ = 16;
constexpr int L_ = 4096;
constexpr int F_ = 512;
constexpr int H_ = 512;
constexpr int CT = 32;           // chunk length along L
constexpr int NC = L_ / CT;      // 128 chunks
constexpr int HB = 256;          // h-range per block in gemm kernel
constexpr int XROW = 520;        // padded LDS row (ushorts): 512 + 8 -> 1040B, 65 slots -> conflict-free
constexpr int SROW = 257;        // padded scan-buffer row (float2)

static __device__ __forceinline__ unsigned short f2bf(float f) {
  union { float f; unsigned u; } v; v.f = f;
  unsigned r = (v.u + 0x7FFFu + ((v.u >> 16) & 1u)) >> 16;   // RNE
  return (unsigned short)r;
}

// ---------------- Kernel 1: pack B_real/B_img into MFMA B-fragment order (bf16) ----
// Bp[ht][fk][lane][j] = B[f = fk*32 + (lane>>4)*8 + j][h = ht*16 + (lane&15)]
__global__ void bprep_kernel(const float* __restrict__ BR, const float* __restrict__ BI,
                             s16x8* __restrict__ BpR, s16x8* __restrict__ BpI) {
  int ht = blockIdx.x >> 4;   // 0..31
  int fk = blockIdx.x & 15;   // 0..15
  int l  = threadIdx.x;       // 0..63
  int h  = ht * 16 + (l & 15);
  int f0 = fk * 32 + (l >> 4) * 8;
  s16x8 r, im;
#pragma unroll
  for (int j = 0; j < 8; ++j) {
    r[j]  = (short)f2bf(BR[(size_t)(f0 + j) * H_ + h]);
    im[j] = (short)f2bf(BI[(size_t)(f0 + j) * H_ + h]);
  }
  int idx = (ht * 16 + fk) * 64 + l;
  BpR[idx] = r;
  BpI[idx] = im;
}

// ---------------- Kernel 2: fused GEMM (bf16 MFMA) + local (zero-init) scan -------
// grid: (hs=2, c=NC, b=B_), block: 256 threads (4 waves)
__global__ __launch_bounds__(256, 2) void gemm_scan_kernel(
    const float* __restrict__ x,
    const s16x8* __restrict__ BpR, const s16x8* __restrict__ BpI,
    const float* __restrict__ nu, const float* __restrict__ theta,
    const float* __restrict__ delta,
    float* __restrict__ out, float* __restrict__ ER, float* __restrict__ EI) {
  __shared__ __align__(16) unsigned char smem[CT * SROW * 8];   // 65792 B (xs aliases sb)
  unsigned short* xs = (unsigned short*)smem;                   // [CT][XROW] bf16
  float2* sb = (float2*)smem;                                   // [CT][SROW] complex

  const int hs   = blockIdx.x;   // 0..1
  const int c    = blockIdx.y;   // 0..NC-1
  const int b    = blockIdx.z;   // 0..B_-1
  const int tid  = threadIdx.x;
  const int lane = tid & 63;
  const int w    = tid >> 6;     // wave id 0..3

  // ---- stage x chunk (CT x F_) fp32 -> bf16 into LDS, coalesced float4 loads ----
  const float* xp = x + (size_t)(b * L_ + c * CT) * F_;
#pragma unroll
  for (int i = 0; i < 8; ++i) {
    int row = i * 4 + (tid >> 6);
    int col = (tid & 63) * 8;
    const float4 v0 = *(const float4*)(xp + row * F_ + col);
    const float4 v1 = *(const float4*)(xp + row * F_ + col + 4);
    s16x8 pk;
    pk[0] = (short)f2bf(v0.x); pk[1] = (short)f2bf(v0.y);
    pk[2] = (short)f2bf(v0.z); pk[3] = (short)f2bf(v0.w);
    pk[4] = (short)f2bf(v1.x); pk[5] = (short)f2bf(v1.y);
    pk[6] = (short)f2bf(v1.z); pk[7] = (short)f2bf(v1.w);
    *(s16x8*)(xs + row * XROW + col) = pk;
  }
  __syncthreads();

  // ---- MFMA GEMM: out tile (CT=32 t) x (64 h per wave), accumulate R and I ----
  f32x4 accR[2][4], accI[2][4];
#pragma unroll
  for (int tt = 0; tt < 2; ++tt)
#pragma unroll
    for (int j = 0; j < 4; ++j) {
      accR[tt][j] = (f32x4){0.f, 0.f, 0.f, 0.f};
      accI[tt][j] = (f32x4){0.f, 0.f, 0.f, 0.f};
    }

#pragma unroll 4
  for (int fk = 0; fk < 16; ++fk) {
    s16x8 a[2];
#pragma unroll
    for (int tt = 0; tt < 2; ++tt)
      a[tt] = *(const s16x8*)(xs + (tt * 16 + (lane & 15)) * XROW + fk * 32 + (lane >> 4) * 8);
#pragma unroll
    for (int j = 0; j < 4; ++j) {
      int ht = hs * 16 + w * 4 + j;                // global h-tile 0..31
      s16x8 br = BpR[(ht * 16 + fk) * 64 + lane];
      s16x8 bi = BpI[(ht * 16 + fk) * 64 + lane];
#pragma unroll
      for (int tt = 0; tt < 2; ++tt) {
        accR[tt][j] = __builtin_amdgcn_mfma_f32_16x16x32_bf16(a[tt], br, accR[tt][j], 0, 0, 0);
        accI[tt][j] = __builtin_amdgcn_mfma_f32_16x16x32_bf16(a[tt], bi, accI[tt][j], 0, 0, 0);
      }
    }
  }
  __syncthreads();   // xs no longer needed; sb aliases it

  // ---- dump accumulators to scan buffer: C/D layout col=lane&15, row=(lane>>4)*4+reg
#pragma unroll
  for (int tt = 0; tt < 2; ++tt)
#pragma unroll
    for (int j = 0; j < 4; ++j)
#pragma unroll
      for (int r = 0; r < 4; ++r) {
        int t  = tt * 16 + (lane >> 4) * 4 + r;
        int hb = (w * 4 + j) * 16 + (lane & 15);
        sb[t * SROW + hb] = make_float2(accR[tt][j][r], accI[tt][j][r]);
      }
  __syncthreads();

  // ---- local scan, one thread per h (256 threads = HB) ----
  {
    int hb = tid;
    int hg = hs * HB + hb;
    float dl  = delta[hg];
    float mag = expf(-expf(nu[hg]));
    float lr  = mag * cosf(theta[hg]);
    float li  = mag * sinf(theta[hg]);
    float sR = 0.f, sI = 0.f;
    float* op = out + (size_t)(b * L_ + c * CT) * H_ + hg;
#pragma unroll 4
    for (int t = 0; t < CT; ++t) {
      float2 u = sb[t * SROW + hb];
      float uR = dl * u.x, uI = dl * u.y;
      float nR = lr * sR - li * sI + uR;
      float nI = lr * sI + li * sR + uI;
      sR = nR; sI = nI;
      op[(size_t)t * H_] = sR;
    }
    size_t eidx = (size_t)(b * NC + c) * H_ + hg;
    ER[eidx] = sR;
    EI[eidx] = sI;
  }
}

// ---------------- Kernel 3: chunk-level combine (E -> H0 in place) ---------------
__global__ void combine_kernel(const float* __restrict__ nu, const float* __restrict__ theta,
                               const float* __restrict__ h0r, const float* __restrict__ h0i,
                               float* __restrict__ ER, float* __restrict__ EI) {
  int g = blockIdx.x * blockDim.x + threadIdx.x;   // 0..8191
  int b = g >> 9;
  int h = g & (H_ - 1);
  float mag = expf(-expf(nu[h]));
  float lr  = mag * cosf(theta[h]);
  float li  = mag * sinf(theta[h]);
  // lam^CT by repeated squaring (CT = 32 = 2^5)
  float pr = lr, pi = li;
#pragma unroll
  for (int s = 0; s < 5; ++s) {
    float nr = pr * pr - pi * pi;
    float ni = 2.f * pr * pi;
    pr = nr; pi = ni;
  }
  float sR = h0r[h], sI = h0i[h];   // state before chunk 0 is h0
  for (int cc = 0; cc < NC; ++cc) {
    size_t idx = (size_t)(b * NC + cc) * H_ + h;
    float tR = ER[idx], tI = EI[idx];
    ER[idx] = sR; EI[idx] = sI;     // becomes H0_c
    float nR = pr * sR - pi * sI + tR;
    float nI = pr * sI + pi * sR + tI;
    sR = nR; sI = nI;
  }
}

// ---------------- Kernel 4: fixup out += Re(lam^{k+1} * H0_c) --------------------
__global__ void fixup_kernel(const float* __restrict__ nu, const float* __restrict__ theta,
                             const float* __restrict__ ER, const float* __restrict__ EI,
                             float* __restrict__ out) {
  int c = blockIdx.x, b = blockIdx.y;
  int h = threadIdx.x;   // 512
  size_t idx = (size_t)(b * NC + c) * H_ + h;
  float hR = ER[idx], hI = EI[idx];
  float mag = expf(-expf(nu[h]));
  float lr  = mag * cosf(theta[h]);
  float li  = mag * sinf(theta[h]);
  float pr = lr, pi = li;   // lam^1
  float* op = out + (size_t)(b * L_ + c * CT) * H_ + h;
#pragma unroll 4
  for (int k = 0; k < CT; ++k) {
    op[(size_t)k * H_] += pr * hR - pi * hI;
    float nr = pr * lr - pi * li;
    float ni = pr * li + pi * lr;
    pr = nr; pi = ni;
  }
}

extern "C" void kernel_launch(void* const* d_in, const int* in_sizes, int n_in,
                              void* d_out, int out_size, void* d_ws, size_t ws_size,
                              hipStream_t stream) {
  const float* x   = (const float*)d_in[0];
  const float* BR  = (const float*)d_in[1];
  const float* BI  = (const float*)d_in[2];
  const float* nu  = (const float*)d_in[3];
  const float* th  = (const float*)d_in[4];
  const float* dl  = (const float*)d_in[5];
  const float* h0r = (const float*)d_in[6];
  const float* h0i = (const float*)d_in[7];
  float* out = (float*)d_out;

  char* wsc = (char*)d_ws;
  s16x8* BpR = (s16x8*)(wsc);
  s16x8* BpI = (s16x8*)(wsc + (512 << 10));
  float* ER  = (float*)(wsc + (1 << 20));
  float* EI  = (float*)(wsc + (1 << 20) + (size_t)B_ * NC * H_ * 4);

  hipLaunchKernelGGL(bprep_kernel, dim3(512), dim3(64), 0, stream, BR, BI, BpR, BpI);
  hipLaunchKernelGGL(gemm_scan_kernel, dim3(2, NC, B_), dim3(256), 0, stream,
                     x, BpR, BpI, nu, th, dl, out, ER, EI);
  hipLaunchKernelGGL(combine_kernel, dim3(16), dim3(512), 0, stream, nu, th, h0r, h0i, ER, EI);
  hipLaunchKernelGGL(fixup_kernel, dim3(NC, B_), dim3(512), 0, stream, nu, th, ER, EI, out);
}